// Round 7
// baseline (129.686 us; speedup 1.0000x reference)
//
#include <hip/hip_runtime.h>

// N=4, C=32, H=W=256, KS=3, O=C*9=288
// ws layout: p [4,32,32,32] (131072 f) | y [4,288,32,32] (1179648 f)
#define N_ 4
#define C_ 32
#define H_ 256
#define W_ 256
#define O_ 288
#define PH 32
#define P_ELEMS (N_*C_*PH*PH)
#define Y_ELEMS (N_*O_*PH*PH)
#define OUT_ELEMS (N_*C_*H_*W_)

typedef float v4f __attribute__((ext_vector_type(4)));

// Kernel 1: psf -> 1/4 bilinear (avg of 2x2 at rows/cols {4o+1,4o+2}) -> maxpool2
__global__ __launch_bounds__(256) void k_downsample(
    const float* __restrict__ psf, float* __restrict__ p) {
  int tid = blockIdx.x * blockDim.x + threadIdx.x;
  if (tid >= P_ELEMS) return;
  int tx = tid & 31;
  int ty = (tid >> 5) & 31;
  int nc = tid >> 10;
  const float* x = psf + (size_t)nc * (H_ * W_);
  float m = -1e30f;
#pragma unroll
  for (int a = 0; a < 2; a++) {
#pragma unroll
    for (int b = 0; b < 2; b++) {
      int r0 = 8 * ty + 4 * a + 1;
      int c0 = 8 * tx + 4 * b;          // 16B-aligned base; cols used: c0+1,c0+2
      const float4 q0 = *(const float4*)(x + r0 * W_ + c0);
      const float4 q1 = *(const float4*)(x + (r0 + 1) * W_ + c0);
      float avg = 0.25f * (q0.y + q0.z + q1.y + q1.z);
      m = fmaxf(m, avg);
    }
  }
  p[tid] = m;
}

// Kernel 2: one block per (n,o); block-uniform weights (scalar loads);
// each thread computes 4 consecutive hw via float4.
__global__ __launch_bounds__(256) void k_conv1x1(
    const float* __restrict__ p, const float* __restrict__ w1,
    const float* __restrict__ b1, const float* __restrict__ ws,
    const float* __restrict__ bs, float* __restrict__ y) {
  int bid = blockIdx.x;           // n*O_ + o
  int n = bid / O_;
  int o = bid - n * O_;
  const float4* p4 = (const float4*)(p + (size_t)n * (C_ * PH * PH));
  const float* w1o = w1 + o * C_;
  const float* wso = ws + o * C_;
  float bb1 = b1[o];
  float bbs = bs[o];
  int t = threadIdx.x;
  float a1x = bb1, a1y = bb1, a1z = bb1, a1w = bb1;
  float a2x = bbs, a2y = bbs, a2z = bbs, a2w = bbs;
#pragma unroll
  for (int c = 0; c < C_; c++) {
    float4 pv = p4[c * 256 + t];
    float u1 = w1o[c], u2 = wso[c];
    a1x = fmaf(pv.x, u1, a1x); a1y = fmaf(pv.y, u1, a1y);
    a1z = fmaf(pv.z, u1, a1z); a1w = fmaf(pv.w, u1, a1w);
    a2x = fmaf(pv.x, u2, a2x); a2y = fmaf(pv.y, u2, a2y);
    a2z = fmaf(pv.z, u2, a2z); a2w = fmaf(pv.w, u2, a2w);
  }
  float4 r;
  r.x = ((a1x >= 0.f) ? a1x : 0.2f * a1x) + a2x;
  r.y = ((a1y >= 0.f) ? a1y : 0.2f * a1y) + a2y;
  r.z = ((a1z >= 0.f) ? a1z : 0.2f * a1z) + a2z;
  r.w = ((a1w >= 0.f) ? a1w : 0.2f * a1w) + a2w;
  ((float4*)(y + (size_t)bid * (PH * PH)))[t] = r;
}

// Kernel 3: fused x8 bilinear upsample + per-pixel 3x3 dynamic filter.
// Block covers one (n,c) plane, h in [8a, 8a+7], all 32 w-groups.
// y staged in LDS (864 floats); fm via L1; out stored non-temporally
// (write-once stream -> keep L2 for fm/y). 8 outputs/thread along w.
__global__ __launch_bounds__(256) void k_fac(
    const float* __restrict__ fm, const float* __restrict__ y,
    float* __restrict__ out) {
  __shared__ float ysh[27 * 32];            // [k*3 + rr][cc]
  int bid = blockIdx.x;
  int work = (bid >> 3) + (bid & 7) * 512;  // XCD-contiguous plane ranges
  int a = work & 31;                        // h-group
  int c = (work >> 5) & 31;
  int n = work >> 10;

  const float* yb = y + ((size_t)(n * O_ + c * 9) << 10);
  int rowg[3];
  rowg[0] = max(a - 1, 0);
  rowg[1] = a;
  rowg[2] = min(a + 1, 31);

  int t = threadIdx.x;
#pragma unroll
  for (int i = t; i < 864; i += 256) {
    int j = i >> 5;                         // staged row 0..26
    int cc = i & 31;
    int k = j / 3;
    int rr = j - 3 * k;
    ysh[i] = yb[(k << 10) + (rowg[rr] << 5) + cc];
  }
  __syncthreads();

  int m = t & 31;
  int h = (a << 3) + (t >> 5);
  float sh = fmaxf(0.125f * (float)h - 0.4375f, 0.f);
  int y0 = (int)sh;
  float wy = sh - (float)y0;
  int rsel0 = y0 - (a - 1);                 // 0 or 1 (a=0 edge -> 1)
  int cm1 = max(m - 1, 0);
  int cp1 = min(m + 1, 31);
  int lo0 = (rsel0 << 5);
  int lo1 = lo0 + 32;

  const float* fb = fm + ((size_t)(n * C_ + c) << 16);

  float acc0 = 0.f, acc1 = 0.f, acc2 = 0.f, acc3 = 0.f;
  float acc4 = 0.f, acc5 = 0.f, acc6 = 0.f, acc7 = 0.f;

#pragma unroll
  for (int ky = 0; ky < 3; ky++) {
    int row = h + ky - 1;
    float fv[10];
    if (row >= 0 && row < 256) {
      const float* fr = fb + (row << 8) + (m << 3);
      float4 q0 = *(const float4*)(fr);
      float4 q1 = *(const float4*)(fr + 4);
      fv[0] = (m > 0) ? fr[-1] : 0.f;
      fv[1] = q0.x; fv[2] = q0.y; fv[3] = q0.z; fv[4] = q0.w;
      fv[5] = q1.x; fv[6] = q1.y; fv[7] = q1.z; fv[8] = q1.w;
      fv[9] = (m < 31) ? fr[8] : 0.f;
    } else {
#pragma unroll
      for (int tt = 0; tt < 10; tt++) fv[tt] = 0.f;
    }
#pragma unroll
    for (int kx = 0; kx < 3; kx++) {
      const float* yp = ysh + 96 * (3 * ky + kx);
      float t0 = yp[lo0 + cm1], t1 = yp[lo0 + m], t2 = yp[lo0 + cp1];
      float u0 = yp[lo1 + cm1], u1 = yp[lo1 + m], u2 = yp[lo1 + cp1];
      float tb0 = fmaf(wy, u0 - t0, t0);
      float tb1 = fmaf(wy, u1 - t1, t1);
      float tb2 = fmaf(wy, u2 - t2, t2);
      float d0 = tb1 - tb0;
      float d1 = tb2 - tb1;
      acc0 = fmaf(fv[0 + kx], fmaf(0.5625f, d0, tb0), acc0);
      acc1 = fmaf(fv[1 + kx], fmaf(0.6875f, d0, tb0), acc1);
      acc2 = fmaf(fv[2 + kx], fmaf(0.8125f, d0, tb0), acc2);
      acc3 = fmaf(fv[3 + kx], fmaf(0.9375f, d0, tb0), acc3);
      acc4 = fmaf(fv[4 + kx], fmaf(0.0625f, d1, tb1), acc4);
      acc5 = fmaf(fv[5 + kx], fmaf(0.1875f, d1, tb1), acc5);
      acc6 = fmaf(fv[6 + kx], fmaf(0.3125f, d1, tb1), acc6);
      acc7 = fmaf(fv[7 + kx], fmaf(0.4375f, d1, tb1), acc7);
    }
  }
  float* ob = out + ((size_t)(((n * C_ + c) << 8) + h) << 8) + (m << 3);
  v4f r0 = {acc0, acc1, acc2, acc3};
  v4f r1 = {acc4, acc5, acc6, acc7};
  __builtin_nontemporal_store(r0, (v4f*)ob);
  __builtin_nontemporal_store(r1, (v4f*)(ob + 4));
}

extern "C" void kernel_launch(void* const* d_in, const int* in_sizes, int n_in,
                              void* d_out, int out_size, void* d_ws,
                              size_t ws_size, hipStream_t stream) {
  const float* psf = (const float*)d_in[0];
  const float* fm = (const float*)d_in[1];
  const float* w1 = (const float*)d_in[2];
  const float* b1 = (const float*)d_in[3];
  const float* ws = (const float*)d_in[4];
  const float* bs = (const float*)d_in[5];
  float* out = (float*)d_out;

  float* p = (float*)d_ws;
  float* y = p + P_ELEMS;

  k_downsample<<<P_ELEMS / 256, 256, 0, stream>>>(psf, p);
  k_conv1x1<<<N_ * O_, 256, 0, stream>>>(p, w1, b1, ws, bs, y);
  k_fac<<<OUT_ELEMS / (8 * 256), 256, 0, stream>>>(fm, y, out);
}

// Round 8
// 124.850 us; speedup vs baseline: 1.0387x; 1.0387x over previous
//
#include <hip/hip_runtime.h>

// N=4, C=32, H=W=256, KS=3, O=C*9=288
// ws layout: p [4,32,32,32] (131072 f) | y [4,288,32,32] (1179648 f)
#define N_ 4
#define C_ 32
#define H_ 256
#define W_ 256
#define O_ 288
#define PH 32
#define P_ELEMS (N_*C_*PH*PH)
#define Y_ELEMS (N_*O_*PH*PH)
#define OUT_ELEMS (N_*C_*H_*W_)

// Kernel 1: psf -> 1/4 bilinear (avg of 2x2 at rows/cols {4o+1,4o+2}) -> maxpool2
__global__ __launch_bounds__(256) void k_downsample(
    const float* __restrict__ psf, float* __restrict__ p) {
  int tid = blockIdx.x * blockDim.x + threadIdx.x;
  if (tid >= P_ELEMS) return;
  int tx = tid & 31;
  int ty = (tid >> 5) & 31;
  int nc = tid >> 10;
  const float* x = psf + (size_t)nc * (H_ * W_);
  float m = -1e30f;
#pragma unroll
  for (int a = 0; a < 2; a++) {
#pragma unroll
    for (int b = 0; b < 2; b++) {
      int r0 = 8 * ty + 4 * a + 1;
      int c0 = 8 * tx + 4 * b;          // 16B-aligned base; cols used: c0+1,c0+2
      const float4 q0 = *(const float4*)(x + r0 * W_ + c0);
      const float4 q1 = *(const float4*)(x + (r0 + 1) * W_ + c0);
      float avg = 0.25f * (q0.y + q0.z + q1.y + q1.z);
      m = fmaxf(m, avg);
    }
  }
  p[tid] = m;
}

// Kernel 2: one block per (n,o); block-uniform weights (scalar loads);
// each thread computes 4 consecutive hw via float4.
__global__ __launch_bounds__(256) void k_conv1x1(
    const float* __restrict__ p, const float* __restrict__ w1,
    const float* __restrict__ b1, const float* __restrict__ ws,
    const float* __restrict__ bs, float* __restrict__ y) {
  int bid = blockIdx.x;           // n*O_ + o
  int n = bid / O_;
  int o = bid - n * O_;
  const float4* p4 = (const float4*)(p + (size_t)n * (C_ * PH * PH));
  const float* w1o = w1 + o * C_;
  const float* wso = ws + o * C_;
  float bb1 = b1[o];
  float bbs = bs[o];
  int t = threadIdx.x;
  float a1x = bb1, a1y = bb1, a1z = bb1, a1w = bb1;
  float a2x = bbs, a2y = bbs, a2z = bbs, a2w = bbs;
#pragma unroll
  for (int c = 0; c < C_; c++) {
    float4 pv = p4[c * 256 + t];
    float u1 = w1o[c], u2 = wso[c];
    a1x = fmaf(pv.x, u1, a1x); a1y = fmaf(pv.y, u1, a1y);
    a1z = fmaf(pv.z, u1, a1z); a1w = fmaf(pv.w, u1, a1w);
    a2x = fmaf(pv.x, u2, a2x); a2y = fmaf(pv.y, u2, a2y);
    a2z = fmaf(pv.z, u2, a2z); a2w = fmaf(pv.w, u2, a2w);
  }
  float4 r;
  r.x = ((a1x >= 0.f) ? a1x : 0.2f * a1x) + a2x;
  r.y = ((a1y >= 0.f) ? a1y : 0.2f * a1y) + a2y;
  r.z = ((a1z >= 0.f) ? a1z : 0.2f * a1z) + a2z;
  r.w = ((a1w >= 0.f) ? a1w : 0.2f * a1w) + a2w;
  ((float4*)(y + (size_t)bid * (PH * PH)))[t] = r;
}

// Kernel 3: fused x8 bilinear upsample + per-pixel 3x3 dynamic filter.
// Block = one (n,c) plane, h in [8a, 8a+7]. Lane m of each 32-lane group
// owns y-column m: 18 coalesced y loads -> vertical blend tb[9] in regs;
// m-1 / m+1 neighbors via width-32 shuffles (no LDS at all). fm edge halo
// (cols 8m-1, 8m+8) also via shuffles of the q0/q1 float4s. 8 out/thread.
__global__ __launch_bounds__(256) void k_fac(
    const float* __restrict__ fm, const float* __restrict__ y,
    float* __restrict__ out) {
  int bid = blockIdx.x;
  int work = (bid >> 3) + (bid & 7) * 512;  // XCD-contiguous plane ranges
  int a = work & 31;                        // h-group
  int c = (work >> 5) & 31;
  int n = work >> 10;
  int t = threadIdx.x;
  int m = t & 31;
  int h = (a << 3) + (t >> 5);

  float sh = fmaxf(0.125f * (float)h - 0.4375f, 0.f);
  int y0 = (int)sh;
  float wy = sh - (float)y0;
  int y1 = min(y0 + 1, 31);

  const float* yb = y + ((size_t)(n * O_ + c * 9) << 10) + m;
  const float* yr0 = yb + (y0 << 5);
  const float* yr1 = yb + (y1 << 5);
  float tb[9];
#pragma unroll
  for (int k = 0; k < 9; k++) {
    float t0 = yr0[k << 10];
    float u0 = yr1[k << 10];
    tb[k] = fmaf(wy, u0 - t0, t0);
  }
  int cm1 = max(m - 1, 0);
  int cp1 = min(m + 1, 31);

  const float* fb = fm + ((size_t)(n * C_ + c) << 16);

  float acc0 = 0.f, acc1 = 0.f, acc2 = 0.f, acc3 = 0.f;
  float acc4 = 0.f, acc5 = 0.f, acc6 = 0.f, acc7 = 0.f;

#pragma unroll
  for (int ky = 0; ky < 3; ky++) {
    int row = h + ky - 1;
    float fv[10];
    if (row >= 0 && row < 256) {            // uniform within each 32-lane group
      const float* fr = fb + (row << 8) + (m << 3);
      float4 q0 = *(const float4*)(fr);
      float4 q1 = *(const float4*)(fr + 4);
      float left = __shfl(q1.w, cm1, 32);   // lane m-1's col 8m-1
      float right = __shfl(q0.x, cp1, 32);  // lane m+1's col 8m+8
      fv[0] = (m > 0) ? left : 0.f;
      fv[1] = q0.x; fv[2] = q0.y; fv[3] = q0.z; fv[4] = q0.w;
      fv[5] = q1.x; fv[6] = q1.y; fv[7] = q1.z; fv[8] = q1.w;
      fv[9] = (m < 31) ? right : 0.f;
    } else {
#pragma unroll
      for (int tt = 0; tt < 10; tt++) fv[tt] = 0.f;
    }
#pragma unroll
    for (int kx = 0; kx < 3; kx++) {
      int k = 3 * ky + kx;
      float tbm = tb[k];
      float tbl = __shfl(tbm, cm1, 32);     // clamped col m-1
      float tbr = __shfl(tbm, cp1, 32);     // clamped col m+1
      float d0 = tbm - tbl;                 // 0 at m==0 (clamp) -> exact
      float d1 = tbr - tbm;                 // 0 at m==31
      acc0 = fmaf(fv[0 + kx], fmaf(0.5625f, d0, tbl), acc0);
      acc1 = fmaf(fv[1 + kx], fmaf(0.6875f, d0, tbl), acc1);
      acc2 = fmaf(fv[2 + kx], fmaf(0.8125f, d0, tbl), acc2);
      acc3 = fmaf(fv[3 + kx], fmaf(0.9375f, d0, tbl), acc3);
      acc4 = fmaf(fv[4 + kx], fmaf(0.0625f, d1, tbm), acc4);
      acc5 = fmaf(fv[5 + kx], fmaf(0.1875f, d1, tbm), acc5);
      acc6 = fmaf(fv[6 + kx], fmaf(0.3125f, d1, tbm), acc6);
      acc7 = fmaf(fv[7 + kx], fmaf(0.4375f, d1, tbm), acc7);
    }
  }
  float* ob = out + ((size_t)(((n * C_ + c) << 8) + h) << 8) + (m << 3);
  float4 r0 = {acc0, acc1, acc2, acc3};
  float4 r1 = {acc4, acc5, acc6, acc7};
  *(float4*)(ob) = r0;
  *(float4*)(ob + 4) = r1;
}

extern "C" void kernel_launch(void* const* d_in, const int* in_sizes, int n_in,
                              void* d_out, int out_size, void* d_ws,
                              size_t ws_size, hipStream_t stream) {
  const float* psf = (const float*)d_in[0];
  const float* fm = (const float*)d_in[1];
  const float* w1 = (const float*)d_in[2];
  const float* b1 = (const float*)d_in[3];
  const float* ws = (const float*)d_in[4];
  const float* bs = (const float*)d_in[5];
  float* out = (float*)d_out;

  float* p = (float*)d_ws;
  float* y = p + P_ELEMS;

  k_downsample<<<P_ELEMS / 256, 256, 0, stream>>>(psf, p);
  k_conv1x1<<<N_ * O_, 256, 0, stream>>>(p, w1, b1, ws, bs, y);
  k_fac<<<OUT_ELEMS / (8 * 256), 256, 0, stream>>>(fm, y, out);
}

// Round 9
// 123.315 us; speedup vs baseline: 1.0517x; 1.0124x over previous
//
#include <hip/hip_runtime.h>

// N=4, C=32, H=W=256, KS=3, O=C*9=288
// ws layout: p [4,32,32,32] (131072 f) | y [4,288,32,32] (1179648 f)
#define N_ 4
#define C_ 32
#define H_ 256
#define W_ 256
#define O_ 288
#define PH 32
#define P_ELEMS (N_*C_*PH*PH)
#define Y_ELEMS (N_*O_*PH*PH)
#define OUT_ELEMS (N_*C_*H_*W_)

// Kernel 1: psf -> 1/4 bilinear (avg of 2x2 at rows/cols {4o+1,4o+2}) -> maxpool2
__global__ __launch_bounds__(256) void k_downsample(
    const float* __restrict__ psf, float* __restrict__ p) {
  int tid = blockIdx.x * blockDim.x + threadIdx.x;
  if (tid >= P_ELEMS) return;
  int tx = tid & 31;
  int ty = (tid >> 5) & 31;
  int nc = tid >> 10;
  const float* x = psf + (size_t)nc * (H_ * W_);
  float m = -1e30f;
#pragma unroll
  for (int a = 0; a < 2; a++) {
#pragma unroll
    for (int b = 0; b < 2; b++) {
      int r0 = 8 * ty + 4 * a + 1;
      int c0 = 8 * tx + 4 * b;          // 16B-aligned base; cols used: c0+1,c0+2
      const float4 q0 = *(const float4*)(x + r0 * W_ + c0);
      const float4 q1 = *(const float4*)(x + (r0 + 1) * W_ + c0);
      float avg = 0.25f * (q0.y + q0.z + q1.y + q1.z);
      m = fmaxf(m, avg);
    }
  }
  p[tid] = m;
}

// Kernel 2: one block per (n,o); block-uniform weights (scalar loads);
// each thread computes 4 consecutive hw via float4.
__global__ __launch_bounds__(256) void k_conv1x1(
    const float* __restrict__ p, const float* __restrict__ w1,
    const float* __restrict__ b1, const float* __restrict__ ws,
    const float* __restrict__ bs, float* __restrict__ y) {
  int bid = blockIdx.x;           // n*O_ + o
  int n = bid / O_;
  int o = bid - n * O_;
  const float4* p4 = (const float4*)(p + (size_t)n * (C_ * PH * PH));
  const float* w1o = w1 + o * C_;
  const float* wso = ws + o * C_;
  float bb1 = b1[o];
  float bbs = bs[o];
  int t = threadIdx.x;
  float a1x = bb1, a1y = bb1, a1z = bb1, a1w = bb1;
  float a2x = bbs, a2y = bbs, a2z = bbs, a2w = bbs;
#pragma unroll
  for (int c = 0; c < C_; c++) {
    float4 pv = p4[c * 256 + t];
    float u1 = w1o[c], u2 = wso[c];
    a1x = fmaf(pv.x, u1, a1x); a1y = fmaf(pv.y, u1, a1y);
    a1z = fmaf(pv.z, u1, a1z); a1w = fmaf(pv.w, u1, a1w);
    a2x = fmaf(pv.x, u2, a2x); a2y = fmaf(pv.y, u2, a2y);
    a2z = fmaf(pv.z, u2, a2z); a2w = fmaf(pv.w, u2, a2w);
  }
  float4 r;
  r.x = ((a1x >= 0.f) ? a1x : 0.2f * a1x) + a2x;
  r.y = ((a1y >= 0.f) ? a1y : 0.2f * a1y) + a2y;
  r.z = ((a1z >= 0.f) ? a1z : 0.2f * a1z) + a2z;
  r.w = ((a1w >= 0.f) ? a1w : 0.2f * a1w) + a2w;
  ((float4*)(y + (size_t)bid * (PH * PH)))[t] = r;
}

// Kernel 3: fused x8 bilinear upsample + per-pixel 3x3 dynamic filter.
// h-pair blocking: each thread computes rows (h0, h0+1), 8 cols each.
// Exact coincidence: for even h0, rows h0 and h0+1 share the same y-row
// pair (y0,y1) (frac(sh) in {.0625,.3125,.5625,.8125}; +0.125 never crosses
// an integer, clamp region included) -> one set of 18 y-loads feeds both
// rows via two vertical blends (tbA, tbB). fm rows h0-1..h0+2 cover both
// outputs. m-neighbors via width-32 shuffles; fm edge halo via shuffles.
__global__ __launch_bounds__(256) void k_fac(
    const float* __restrict__ fm, const float* __restrict__ y,
    float* __restrict__ out) {
  int bid = blockIdx.x;                     // 2048 blocks
  int work = (bid >> 3) + (bid & 7) * 256;  // XCD-contiguous plane ranges
  int a = work & 15;                        // 16-row h-band
  int c = (work >> 4) & 31;
  int n = work >> 9;
  int t = threadIdx.x;
  int m = t & 31;
  int r = t >> 5;                           // 0..7
  int h0 = (a << 4) + (r << 1);             // even

  float sh0 = fmaxf(0.125f * (float)h0 - 0.4375f, 0.f);
  float sh1 = fmaxf(0.125f * (float)h0 - 0.3125f, 0.f);   // h0+1
  int y0 = (int)sh0;
  float wy0 = sh0 - (float)y0;
  float wy1 = sh1 - (float)y0;              // same y0 (see proof above)
  int y1 = min(y0 + 1, 31);

  const float* yb = y + ((size_t)(n * O_ + c * 9) << 10) + m;
  const float* yr0 = yb + (y0 << 5);
  const float* yr1 = yb + (y1 << 5);
  float tbA[9], tbB[9];
#pragma unroll
  for (int k = 0; k < 9; k++) {
    float t0 = yr0[k << 10];
    float u0 = yr1[k << 10];
    float d = u0 - t0;
    tbA[k] = fmaf(wy0, d, t0);
    tbB[k] = fmaf(wy1, d, t0);
  }
  int cm1 = max(m - 1, 0);
  int cp1 = min(m + 1, 31);

  const float* fb = fm + ((size_t)(n * C_ + c) << 16);

  float acc[16];
#pragma unroll
  for (int j = 0; j < 16; j++) acc[j] = 0.f;

#pragma unroll
  for (int i = 0; i < 4; i++) {             // fm rows h0-1 .. h0+2
    int row = h0 - 1 + i;
    float fv[10];
    if (row >= 0 && row < 256) {            // uniform within 32-lane group
      const float* fr = fb + (row << 8) + (m << 3);
      float4 q0 = *(const float4*)(fr);
      float4 q1 = *(const float4*)(fr + 4);
      float left = __shfl(q1.w, cm1, 32);
      float right = __shfl(q0.x, cp1, 32);
      fv[0] = (m > 0) ? left : 0.f;
      fv[1] = q0.x; fv[2] = q0.y; fv[3] = q0.z; fv[4] = q0.w;
      fv[5] = q1.x; fv[6] = q1.y; fv[7] = q1.z; fv[8] = q1.w;
      fv[9] = (m < 31) ? right : 0.f;
    } else {
#pragma unroll
      for (int tt = 0; tt < 10; tt++) fv[tt] = 0.f;
    }
    // row contributes as ky=i to output h0 (i<=2), ky=i-1 to h0+1 (i>=1)
#pragma unroll
    for (int kx = 0; kx < 3; kx++) {
      if (i <= 2) {
        int k = 3 * i + kx;
        float tbm = tbA[k];
        float tbl = __shfl(tbm, cm1, 32);
        float tbr = __shfl(tbm, cp1, 32);
        float d0 = tbm - tbl;
        float d1 = tbr - tbm;
        acc[0] = fmaf(fv[0 + kx], fmaf(0.5625f, d0, tbl), acc[0]);
        acc[1] = fmaf(fv[1 + kx], fmaf(0.6875f, d0, tbl), acc[1]);
        acc[2] = fmaf(fv[2 + kx], fmaf(0.8125f, d0, tbl), acc[2]);
        acc[3] = fmaf(fv[3 + kx], fmaf(0.9375f, d0, tbl), acc[3]);
        acc[4] = fmaf(fv[4 + kx], fmaf(0.0625f, d1, tbm), acc[4]);
        acc[5] = fmaf(fv[5 + kx], fmaf(0.1875f, d1, tbm), acc[5]);
        acc[6] = fmaf(fv[6 + kx], fmaf(0.3125f, d1, tbm), acc[6]);
        acc[7] = fmaf(fv[7 + kx], fmaf(0.4375f, d1, tbm), acc[7]);
      }
      if (i >= 1) {
        int k = 3 * (i - 1) + kx;
        float tbm = tbB[k];
        float tbl = __shfl(tbm, cm1, 32);
        float tbr = __shfl(tbm, cp1, 32);
        float d0 = tbm - tbl;
        float d1 = tbr - tbm;
        acc[8]  = fmaf(fv[0 + kx], fmaf(0.5625f, d0, tbl), acc[8]);
        acc[9]  = fmaf(fv[1 + kx], fmaf(0.6875f, d0, tbl), acc[9]);
        acc[10] = fmaf(fv[2 + kx], fmaf(0.8125f, d0, tbl), acc[10]);
        acc[11] = fmaf(fv[3 + kx], fmaf(0.9375f, d0, tbl), acc[11]);
        acc[12] = fmaf(fv[4 + kx], fmaf(0.0625f, d1, tbm), acc[12]);
        acc[13] = fmaf(fv[5 + kx], fmaf(0.1875f, d1, tbm), acc[13]);
        acc[14] = fmaf(fv[6 + kx], fmaf(0.3125f, d1, tbm), acc[14]);
        acc[15] = fmaf(fv[7 + kx], fmaf(0.4375f, d1, tbm), acc[15]);
      }
    }
  }
  float* ob = out + ((size_t)(((n * C_ + c) << 8) + h0) << 8) + (m << 3);
  float4 r0 = {acc[0], acc[1], acc[2], acc[3]};
  float4 r1 = {acc[4], acc[5], acc[6], acc[7]};
  float4 r2 = {acc[8], acc[9], acc[10], acc[11]};
  float4 r3 = {acc[12], acc[13], acc[14], acc[15]};
  *(float4*)(ob) = r0;
  *(float4*)(ob + 4) = r1;
  *(float4*)(ob + 256) = r2;               // row h0+1
  *(float4*)(ob + 260) = r3;
}

extern "C" void kernel_launch(void* const* d_in, const int* in_sizes, int n_in,
                              void* d_out, int out_size, void* d_ws,
                              size_t ws_size, hipStream_t stream) {
  const float* psf = (const float*)d_in[0];
  const float* fm = (const float*)d_in[1];
  const float* w1 = (const float*)d_in[2];
  const float* b1 = (const float*)d_in[3];
  const float* ws = (const float*)d_in[4];
  const float* bs = (const float*)d_in[5];
  float* out = (float*)d_out;

  float* p = (float*)d_ws;
  float* y = p + P_ELEMS;

  k_downsample<<<P_ELEMS / 256, 256, 0, stream>>>(psf, p);
  k_conv1x1<<<N_ * O_, 256, 0, stream>>>(p, w1, b1, ws, bs, y);
  k_fac<<<OUT_ELEMS / (16 * 256), 256, 0, stream>>>(fm, y, out);
}